// Round 11
// baseline (169.953 us; speedup 1.0000x reference)
//
#include <hip/hip_runtime.h>

typedef __attribute__((ext_vector_type(8))) short bf16x8;
typedef __attribute__((ext_vector_type(4))) float f32x4;
typedef __attribute__((ext_vector_type(4))) unsigned short u16x4;
typedef __attribute__((ext_vector_type(8))) unsigned short u16x8;

#define MFMA16(a, b, c) __builtin_amdgcn_mfma_f32_16x16x32_bf16((a), (b), (c), 0, 0, 0)

__device__ __forceinline__ ushort f2bf(float f) {
    unsigned u = __float_as_uint(f);
    unsigned r = (u + 0x7FFFu + ((u >> 16) & 1u)) >> 16;
    return (ushort)r;
}
__device__ __forceinline__ float bf2f(ushort s) {
    return __uint_as_float(((unsigned)s) << 16);
}

// async global->LDS, 16B per lane. LDS dest is wave-uniform base + lane*16.
__device__ __forceinline__ void async16(const ushort* g, ushort* l) {
    __builtin_amdgcn_global_load_lds(
        (const __attribute__((address_space(1))) unsigned*)g,
        (__attribute__((address_space(3))) unsigned*)l, 16, 0, 0);
}

#define SBAR()  __builtin_amdgcn_s_barrier()
#define SCHED() __builtin_amdgcn_sched_barrier(0)

// ---------------------------------------------------------------------------
// Kernel 0: fused conversions.
// blocks [0,4608): straight fp32->bf16 of x and Wv.
// blocks [4608,6656): 32x32 transpose-convert of Wk (z=0) and Wq (z=1).
// ---------------------------------------------------------------------------
__global__ __launch_bounds__(256) void cvt_all(
    const float* __restrict__ x,  const float* __restrict__ wk,
    const float* __restrict__ wq, const float* __restrict__ wv,
    ushort* __restrict__ xb,  ushort* __restrict__ wvb,
    ushort* __restrict__ wkt, ushort* __restrict__ wqt)
{
    __shared__ float t[32][33];
    int bx = blockIdx.x;
    if (bx < 4608) {
        const size_t XN = (size_t)8192 * 1024;
        size_t idx = ((size_t)bx * 256 + threadIdx.x) * 8;
        const float* s;
        ushort* d;
        if (idx < XN) { s = x + idx; d = xb + idx; }
        else          { s = wv + (idx - XN); d = wvb + (idx - XN); }
        float4 a = *(const float4*)s;
        float4 b = *(const float4*)(s + 4);
        u16x8 p;
        p[0] = f2bf(a.x); p[1] = f2bf(a.y); p[2] = f2bf(a.z); p[3] = f2bf(a.w);
        p[4] = f2bf(b.x); p[5] = f2bf(b.y); p[6] = f2bf(b.z); p[7] = f2bf(b.w);
        *(u16x8*)d = p;
    } else {
        bx -= 4608;
        const int z  = bx >> 10;
        const int tb = bx & 1023;
        const int e0 = (tb & 31) * 32, d0 = (tb >> 5) * 32;
        const float* src = z ? wq : wk;
        ushort*      dst = z ? wqt : wkt;
        const int tx = threadIdx.x & 31, ty = threadIdx.x >> 5;
#pragma unroll
        for (int r = 0; r < 4; ++r)
            t[ty + 8 * r][tx] = src[(size_t)(e0 + ty + 8 * r) * 1024 + d0 + tx];
        __syncthreads();
#pragma unroll
        for (int r = 0; r < 4; ++r)
            dst[(size_t)(d0 + ty + 8 * r) * 1024 + e0 + tx] = f2bf(t[tx][ty + 8 * r]);
    }
}

// ---------------------------------------------------------------------------
// 2-phase 128x128 core (kept for m_gemm). 256 threads.
// ---------------------------------------------------------------------------
__device__ __forceinline__ void mma_tile(
    const ushort* __restrict__ A, int lda, int abase,
    const ushort* __restrict__ B, int ldb, int bbase,
    int ktiles,
    ushort* As, ushort* Bs, f32x4 (&acc)[4][4])
{
    const int tid  = threadIdx.x;
    const int lane = tid & 63, wid = tid >> 6;
    const int wr = wid >> 1, wc = wid & 1;
    const int lrow = lane & 15, kgrp = lane >> 4;
    const int ci = lane >> 3;
    const int cc = (lane & 7) * 8;

#pragma unroll
    for (int m = 0; m < 4; ++m)
#pragma unroll
        for (int n = 0; n < 4; ++n) acc[m][n] = (f32x4){0.f, 0.f, 0.f, 0.f};

    for (int kt = 0; kt < ktiles; ++kt) {
        const int k0 = kt * 64;
#pragma unroll
        for (int i = 0; i < 4; ++i) {
            const int r = (wid * 4 + i) * 8 + ci;
            async16(&A[(size_t)(abase + r) * lda + k0 + cc], &As[(wid * 4 + i) * 512]);
            async16(&B[(size_t)(bbase + r) * ldb + k0 + cc], &Bs[(wid * 4 + i) * 512]);
        }
        __syncthreads();
#pragma unroll
        for (int kk = 0; kk < 2; ++kk) {
            bf16x8 af[4], bfr[4];
#pragma unroll
            for (int m = 0; m < 4; ++m)
                af[m] = *(const bf16x8*)&As[(wr * 64 + m * 16 + lrow) * 64 + kk * 32 + kgrp * 8];
#pragma unroll
            for (int n = 0; n < 4; ++n)
                bfr[n] = *(const bf16x8*)&Bs[(wc * 64 + n * 16 + lrow) * 64 + kk * 32 + kgrp * 8];
#pragma unroll
            for (int m = 0; m < 4; ++m)
#pragma unroll
                for (int n = 0; n < 4; ++n)
                    acc[m][n] = MFMA16(af[m], bfr[n], acc[m][n]);
        }
        __syncthreads();
    }
}

// ---------------------------------------------------------------------------
// 8-phase 256x256 core (tv, scores), m201-style steady schedule.
// 512 threads = 8 waves (2 Mrows x 4 Ncols).
// LDS per operand: 4 K-half slots [t&1][kk][256 rows][32 elems] (16 KB each).
// Granule XOR swizzle: phys granule = logical ^ ((row>>2)&3) -> quarter-wave
// spreads over 4 positions x alternating row-parity bank halves = 2-way (free).
// Stage side uses the inverse involution on the GLOBAL source column
// (linear global_load_lds dest, rule #21 both-sides).
// Stage stream (1 slot per phase): P1: B(t+1)k1, P2: A(t+2)k0, P3: B(t+2)k0,
// P4: A(t+2)k1 + vmcnt(6). Slot-free proof: A[.][0] freed after P1, B[.][0]
// after P2, A[.][1] after P3, B[.][1] after P4 (1 barrier before re-stage).
// Steady ledger at t.P4: in-flight 7 halves (14 loads) ordered
// [A(t+1)k0,B(t+1)k0,A(t+1)k1,B(t+1)k1,A(t+2)k0,B(t+2)k0,A(t+2)k1];
// vmcnt(6) completes oldest 4 = tile t+1 fully resident, leaves t+2's 3.
// Tail: t+2==NT -> vmcnt(0). Prologue: 7 halves + vmcnt(6).
// ---------------------------------------------------------------------------
__device__ __forceinline__ void mma256(
    const ushort* __restrict__ A, int lda, int abase,
    const ushort* __restrict__ B, int ldb, int bbase,
    int NT, ushort* As, ushort* Bs, f32x4 (&acc)[8][4])
{
    const int tid  = threadIdx.x;
    const int lane = tid & 63, w = tid >> 6;
    const int wr = w >> 2, wc = w & 3;
    const int lrow = lane & 15, kgrp = lane >> 4;

    // stage one K-half slot (256 rows x 32 elems) of one operand; 2 loads/thread
    auto stage = [&](int t, int isB, int kk) {
        const ushort* src = isB ? B : A;
        const int ld = isB ? ldb : lda;
        const int rb = isB ? bbase : abase;
        ushort* slot = (isB ? Bs : As) + (size_t)((t & 1) * 2 + kk) * 8192;
#pragma unroll
        for (int i = 0; i < 2; ++i) {
            const int G = (w * 2 + i) * 64 + lane;   // granule 0..1023
            const int r = G >> 2, g = G & 3;
            const int sg = g ^ ((r >> 2) & 3);       // inverse-swizzled src granule
            async16(&src[(size_t)(rb + r) * ld + t * 64 + kk * 32 + sg * 8],
                    slot + (size_t)G * 8);
        }
    };

#pragma unroll
    for (int m = 0; m < 8; ++m)
#pragma unroll
        for (int n = 0; n < 4; ++n) acc[m][n] = (f32x4){0.f, 0.f, 0.f, 0.f};

    // prologue: tile 0 complete + A1k0, B1k0, A1k1 (7 halves)
    stage(0, 0, 0); stage(0, 1, 0); stage(0, 0, 1); stage(0, 1, 1);
    if (NT > 1) {
        stage(1, 0, 0); stage(1, 1, 0); stage(1, 0, 1);
        asm volatile("s_waitcnt vmcnt(6)" ::: "memory");   // tile 0 resident
    } else {
        asm volatile("s_waitcnt vmcnt(0)" ::: "memory");
    }
    SCHED();
    SBAR();
    SCHED();

    const int pg = (kgrp ^ ((lrow >> 2) & 3)) * 8;   // phys granule offset (elems)

    for (int t = 0; t < NT; ++t) {
        ushort* A0 = As + (size_t)((t & 1) * 2 + 0) * 8192;
        ushort* A1 = As + (size_t)((t & 1) * 2 + 1) * 8192;
        ushort* B0 = Bs + (size_t)((t & 1) * 2 + 0) * 8192;
        ushort* B1 = Bs + (size_t)((t & 1) * 2 + 1) * 8192;
        bf16x8 af[8], bfr[2];

        // ---- P1: (kk0, n0-1); stage B(t+1)k1 ----
#pragma unroll
        for (int m = 0; m < 8; ++m)
            af[m] = *(const bf16x8*)&A0[(wr * 128 + m * 16 + lrow) * 32 + pg];
#pragma unroll
        for (int n = 0; n < 2; ++n)
            bfr[n] = *(const bf16x8*)&B0[(wc * 64 + n * 16 + lrow) * 32 + pg];
        if (t + 1 < NT) stage(t + 1, 1, 1);
        SBAR(); SCHED();
        __builtin_amdgcn_s_setprio(1);
#pragma unroll
        for (int m = 0; m < 8; ++m) {
            acc[m][0] = MFMA16(af[m], bfr[0], acc[m][0]);
            acc[m][1] = MFMA16(af[m], bfr[1], acc[m][1]);
        }
        __builtin_amdgcn_s_setprio(0);
        SBAR(); SCHED();

        // ---- P2: (kk0, n2-3); stage A(t+2)k0 ----
#pragma unroll
        for (int n = 0; n < 2; ++n)
            bfr[n] = *(const bf16x8*)&B0[(wc * 64 + (2 + n) * 16 + lrow) * 32 + pg];
        if (t + 2 < NT) stage(t + 2, 0, 0);
        SBAR(); SCHED();
        __builtin_amdgcn_s_setprio(1);
#pragma unroll
        for (int m = 0; m < 8; ++m) {
            acc[m][2] = MFMA16(af[m], bfr[0], acc[m][2]);
            acc[m][3] = MFMA16(af[m], bfr[1], acc[m][3]);
        }
        __builtin_amdgcn_s_setprio(0);
        SBAR(); SCHED();

        // ---- P3: (kk1, n0-1); stage B(t+2)k0 ----
#pragma unroll
        for (int m = 0; m < 8; ++m)
            af[m] = *(const bf16x8*)&A1[(wr * 128 + m * 16 + lrow) * 32 + pg];
#pragma unroll
        for (int n = 0; n < 2; ++n)
            bfr[n] = *(const bf16x8*)&B1[(wc * 64 + n * 16 + lrow) * 32 + pg];
        if (t + 2 < NT) stage(t + 2, 1, 0);
        SBAR(); SCHED();
        __builtin_amdgcn_s_setprio(1);
#pragma unroll
        for (int m = 0; m < 8; ++m) {
            acc[m][0] = MFMA16(af[m], bfr[0], acc[m][0]);
            acc[m][1] = MFMA16(af[m], bfr[1], acc[m][1]);
        }
        __builtin_amdgcn_s_setprio(0);
        SBAR(); SCHED();

        // ---- P4: (kk1, n2-3); stage A(t+2)k1 + counted wait ----
#pragma unroll
        for (int n = 0; n < 2; ++n)
            bfr[n] = *(const bf16x8*)&B1[(wc * 64 + (2 + n) * 16 + lrow) * 32 + pg];
        if (t + 2 < NT) {
            stage(t + 2, 0, 1);
            asm volatile("s_waitcnt vmcnt(6)" ::: "memory");   // tile t+1 resident
        } else if (t + 1 < NT) {
            asm volatile("s_waitcnt vmcnt(0)" ::: "memory");   // tile t+1 resident
        }
        SCHED();
        SBAR(); SCHED();
        __builtin_amdgcn_s_setprio(1);
#pragma unroll
        for (int m = 0; m < 8; ++m) {
            acc[m][2] = MFMA16(af[m], bfr[0], acc[m][2]);
            acc[m][3] = MFMA16(af[m], bfr[1], acc[m][3]);
        }
        __builtin_amdgcn_s_setprio(0);
        SBAR(); SCHED();
    }
}

// ---------------------------------------------------------------------------
// Kernel 1: Mtr[f][d] = (sum_e Wkt[f][e] * Wqt[d][e]) / 32  (scale folded).
// ---------------------------------------------------------------------------
__global__ __launch_bounds__(256) void m_gemm(
    const ushort* __restrict__ Wkt, const ushort* __restrict__ Wqt,
    ushort* __restrict__ Mtr)
{
    __shared__ ushort As[128 * 64];
    __shared__ ushort Bs[128 * 64];
    const int fbase = blockIdx.x * 128;
    const int dbase = blockIdx.y * 128;

    f32x4 acc[4][4];
    mma_tile(Wkt, 1024, fbase, Wqt, 1024, dbase, 16, As, Bs, acc);

    const int lane = threadIdx.x & 63, wid = threadIdx.x >> 6;
    const int wr = wid >> 1, wc = wid & 1;
    const int lrow = lane & 15, kgrp = lane >> 4;
#pragma unroll
    for (int m = 0; m < 4; ++m)
#pragma unroll
        for (int n = 0; n < 4; ++n)
#pragma unroll
            for (int r = 0; r < 4; ++r) {
                const int gf = fbase + wr * 64 + m * 16 + kgrp * 4 + r;
                const int gd = dbase + wc * 64 + n * 16 + lrow;
                Mtr[(size_t)gf * 1024 + gd] = f2bf(acc[m][n][r] * 0.03125f);
            }
}

// ---------------------------------------------------------------------------
// Kernel 2: 8-phase. z=0: T = xb @ Mtr^T -> Tb row-major. z=1: V -> Vt transposed.
// ---------------------------------------------------------------------------
__global__ __launch_bounds__(512, 2) void tv_gemm8(
    const ushort* __restrict__ xb, const ushort* __restrict__ Mtr,
    const ushort* __restrict__ Wvb,
    ushort* __restrict__ Tb, ushort* __restrict__ Vt)
{
    __shared__ ushort As[4 * 8192];
    __shared__ ushort Bs[4 * 8192];

    const int z = blockIdx.z;
    const ushort* Bmat = z ? Wvb : Mtr;
    const int mbase = blockIdx.x * 256;
    const int nbase = blockIdx.y * 256;

    f32x4 acc[8][4];
    mma256(xb, 1024, mbase, Bmat, 1024, nbase, 16, As, Bs, acc);

    const int lane = threadIdx.x & 63, w = threadIdx.x >> 6;
    const int wr = w >> 2, wc = w & 3;
    const int lrow = lane & 15, kgrp = lane >> 4;

    if (z == 1) {
        const int b  = mbase >> 11;
        const int s0 = mbase & 2047;
        ushort* VtB = Vt + (size_t)b * 1024 * 2048;
#pragma unroll
        for (int m = 0; m < 8; ++m)
#pragma unroll
            for (int n = 0; n < 4; ++n) {
                u16x4 pk;
#pragma unroll
                for (int r = 0; r < 4; ++r) pk[r] = f2bf(acc[m][n][r]);
                const int d = nbase + wc * 64 + n * 16 + lrow;
                const int s = s0 + wr * 128 + m * 16 + kgrp * 4;
                *(u16x4*)&VtB[(size_t)d * 2048 + s] = pk;
            }
    } else {
#pragma unroll
        for (int m = 0; m < 8; ++m)
#pragma unroll
            for (int n = 0; n < 4; ++n)
#pragma unroll
                for (int r = 0; r < 4; ++r) {
                    const int gr = mbase + wr * 128 + m * 16 + kgrp * 4 + r;
                    const int gc = nbase + wc * 64 + n * 16 + lrow;
                    Tb[(size_t)gr * 1024 + gc] = f2bf(acc[m][n][r]);
                }
    }
}

// ---------------------------------------------------------------------------
// Kernel 3: 8-phase scores, lower-tri 256-tiles. Stores UNNORMALIZED
// p = exp(s) with causal mask, AND writes per-(row, jt) partial row-sums
// rsum[b][jt][row] (exactly one writer each -> deterministic).
// ---------------------------------------------------------------------------
__global__ __launch_bounds__(512, 2) void scores_gemm8(
    const ushort* __restrict__ Tb, const ushort* __restrict__ xb,
    ushort* __restrict__ Sall, float* __restrict__ rsum)
{
    __shared__ ushort As[4 * 8192];
    __shared__ ushort Bs[4 * 8192];

    ushort* S = Sall + (size_t)blockIdx.y * 2048 * 2048;
    const int rb = blockIdx.y * 2048;

    int t = blockIdx.x;
    int it = (int)((sqrtf(8.0f * (float)t + 1.0f) - 1.0f) * 0.5f);
    while ((it + 1) * (it + 2) / 2 <= t) ++it;
    while (it * (it + 1) / 2 > t) --it;
    const int jt = t - it * (it + 1) / 2;
    const int ibase = it * 256, jbase = jt * 256;
    const bool diag = (it == jt);

    f32x4 acc[8][4];
    mma256(Tb, 1024, rb + ibase, xb, 1024, rb + jbase, 16, As, Bs, acc);

    const int tid = threadIdx.x;
    const int lane = tid & 63, w = tid >> 6;
    const int wr = w >> 2, wc = w & 3;
    const int lrow = lane & 15, kgrp = lane >> 4;

    float prs[8][4];
#pragma unroll
    for (int m = 0; m < 8; ++m)
#pragma unroll
        for (int r = 0; r < 4; ++r) prs[m][r] = 0.f;

#pragma unroll
    for (int m = 0; m < 8; ++m)
#pragma unroll
        for (int n = 0; n < 4; ++n)
#pragma unroll
            for (int r = 0; r < 4; ++r) {
                const int gi = ibase + wr * 128 + m * 16 + kgrp * 4 + r;
                const int gj = jbase + wc * 64 + n * 16 + lrow;
                float p = __expf(acc[m][n][r]);
                if (diag && gj > gi) p = 0.f;
                S[(size_t)gi * 2048 + gj] = f2bf(p);
                prs[m][r] += p;
            }

    // reduce partial sums over lrow (16 lanes), stash per-wave slice in LDS
    float* psum = (float*)As;   // [2 wr][4 wc][128 rows] = 4 KB (As is dead)
#pragma unroll
    for (int m = 0; m < 8; ++m)
#pragma unroll
        for (int r = 0; r < 4; ++r) {
            float v = prs[m][r];
            v += __shfl_xor(v, 1);
            v += __shfl_xor(v, 2);
            v += __shfl_xor(v, 4);
            v += __shfl_xor(v, 8);
            prs[m][r] = v;
        }
    if (lrow == 0) {
#pragma unroll
        for (int m = 0; m < 8; ++m)
#pragma unroll
            for (int r = 0; r < 4; ++r)
                psum[(wr * 4 + wc) * 128 + m * 16 + kgrp * 4 + r] = prs[m][r];
    }
    __syncthreads();
    if (tid < 256) {
        const int half = tid >> 7, rr = tid & 127;
        float s4 = psum[(half * 4 + 0) * 128 + rr] + psum[(half * 4 + 1) * 128 + rr]
                 + psum[(half * 4 + 2) * 128 + rr] + psum[(half * 4 + 3) * 128 + rr];
        rsum[(size_t)(blockIdx.y * 9 + jt) * 2048 + ibase + tid] = s4;
    }
}

// ---------------------------------------------------------------------------
// PV sub-GEMM: O-rows [it*128, +128) x cols [nbase, +128). Fat single-phase,
// 3-deep prefetch (3 LDS buffers). stage() = 4 loads/thread. Ledger: at the
// in-loop wait, outstanding = {t+1,t+2,t+3} x 4 = 12 -> vmcnt(8) completes
// t+1. Tails: t+3==NT -> vmcnt(4); t+2==NT -> vmcnt(0).
// XOR-16B swizzled LDS. Row normalization from precomputed rsum partials.
// ---------------------------------------------------------------------------
__device__ __forceinline__ void pv_sub(
    const ushort* __restrict__ P, const ushort* __restrict__ Vt,
    float* __restrict__ O, const float* __restrict__ rsb,
    int it, int nbase, ushort* As, ushort* Bs, float* rs)
{
    const int tid  = threadIdx.x;
    const int lane = tid & 63, w = tid >> 6;
    const int wr = w >> 2, wc = w & 3;
    const int lrow = lane & 15, kgrp = lane >> 4;
    const int srow = lane >> 3;
    const int sc16 = (lane & 7) ^ srow;
    const int pbase = it * 128;
    const int NT = 2 * (it + 1);
    const int jtmax = it >> 1;

    auto stage = [&](int t, int slot) {
        ushort* dA = As + (size_t)slot * 8192;
        ushort* dB = Bs + (size_t)slot * 8192;
#pragma unroll
        for (int i = 0; i < 2; ++i) {
            const int rr = (i * 8 + w) * 8 + srow;
            async16(&P [(size_t)(pbase + rr) * 2048 + t * 64 + sc16 * 8],
                    dA + ((i * 8 + w) * 64 + lane) * 8);
            async16(&Vt[(size_t)(nbase + rr) * 2048 + t * 64 + sc16 * 8],
                    dB + ((i * 8 + w) * 64 + lane) * 8);
        }
    };

    // precompute row normalizers (<= 9 partials per row)
    if (tid < 128) {
        float s = 0.f;
        for (int j = 0; j <= jtmax; ++j)
            s += rsb[(size_t)j * 2048 + pbase + tid];
        rs[tid] = 1.0f / s;
    }

    f32x4 acc[4][2];
#pragma unroll
    for (int m = 0; m < 4; ++m)
#pragma unroll
        for (int n = 0; n < 2; ++n) acc[m][n] = (f32x4){0.f, 0.f, 0.f, 0.f};

    stage(0, 0);
    if (NT > 2) {
        stage(1, 1); stage(2, 2);
        asm volatile("s_waitcnt vmcnt(8)" ::: "memory");   // tile 0 resident
    } else {   // NT == 2
        stage(1, 1);
        asm volatile("s_waitcnt vmcnt(4)" ::: "memory");   // tile 0 resident
    }
    SCHED();
    SBAR(); SCHED();

    int bi = 0;
    for (int t = 0; t < NT; ++t) {
        const ushort* Ab = As + (size_t)bi * 8192;
        const ushort* Bb = Bs + (size_t)bi * 8192;
        bf16x8 af[2][4], bq[2][2];
#pragma unroll
        for (int kk = 0; kk < 2; ++kk) {
            const int p16 = (kk * 4 + kgrp) ^ (lrow & 7);
#pragma unroll
            for (int m = 0; m < 4; ++m) {
                const int row = wr * 64 + m * 16 + lrow;
                af[kk][m] = *(const bf16x8*)&Ab[row * 64 + p16 * 8];
            }
#pragma unroll
            for (int n = 0; n < 2; ++n) {
                const int row = wc * 32 + n * 16 + lrow;
                bq[kk][n] = *(const bf16x8*)&Bb[row * 64 + p16 * 8];
            }
        }
        asm volatile("s_waitcnt lgkmcnt(0)" ::: "memory");
        SCHED();
        SBAR(); SCHED();                   // buf[bi] fully read -> released
        if (t + 3 < NT) {
            stage(t + 3, bi);
            asm volatile("s_waitcnt vmcnt(8)" ::: "memory");  // t+1 complete
        } else if (t + 3 == NT) {
            asm volatile("s_waitcnt vmcnt(4)" ::: "memory");  // t+1 complete
        } else if (t + 2 == NT) {
            asm volatile("s_waitcnt vmcnt(0)" ::: "memory");  // t+1 complete
        }
        SCHED();
        SBAR(); SCHED();                   // t+1 resident for all waves
        __builtin_amdgcn_s_setprio(1);
#pragma unroll
        for (int kk = 0; kk < 2; ++kk)
#pragma unroll
            for (int m = 0; m < 4; ++m) {
                acc[m][0] = MFMA16(af[kk][m], bq[kk][0], acc[m][0]);
                acc[m][1] = MFMA16(af[kk][m], bq[kk][1], acc[m][1]);
            }
        __builtin_amdgcn_s_setprio(0);
        bi = (bi == 2) ? 0 : bi + 1;
    }

    __syncthreads();   // rs[] ready (written pre-loop by tid<128)

#pragma unroll
    for (int m = 0; m < 4; ++m)
#pragma unroll
        for (int r = 0; r < 4; ++r) {
            const int ri = wr * 64 + m * 16 + kgrp * 4 + r;
            const float inv = rs[ri];
            const int gi = pbase + ri;
#pragma unroll
            for (int n = 0; n < 2; ++n) {
                const int gc = nbase + wc * 32 + n * 16 + lrow;
                O[(size_t)gi * 1024 + gc] = acc[m][n][r] * inv;
            }
        }
    __syncthreads();
}

// ---------------------------------------------------------------------------
// Kernel 4: O = P @ V with fused normalize. Paired row-tiles (15-bx, bx):
// every block exactly 34 k-tiles. grid (8, 8, 4) = 256 blocks = 1/CU.
// ---------------------------------------------------------------------------
__global__ __launch_bounds__(512, 2) void pv_pair(
    const ushort* __restrict__ Pall, const ushort* __restrict__ Vtall,
    const float* __restrict__ rsum, float* __restrict__ Oall)
{
    __shared__ ushort As[3 * 8192];   // 48 KiB
    __shared__ ushort Bs[3 * 8192];   // 48 KiB
    __shared__ float rs[128];

    const ushort* P  = Pall  + (size_t)blockIdx.z * 2048 * 2048;
    const ushort* Vt = Vtall + (size_t)blockIdx.z * 1024 * 2048;
    const float* rsb = rsum  + (size_t)blockIdx.z * 9 * 2048;
    float*        O  = Oall  + (size_t)blockIdx.z * 2048 * 1024;
    const int nbase = blockIdx.y * 128;

    pv_sub(P, Vt, O, rsb, 15 - (int)blockIdx.x, nbase, As, Bs, rs);
    pv_sub(P, Vt, O, rsb, (int)blockIdx.x,      nbase, As, Bs, rs);
}

// ---------------------------------------------------------------------------
extern "C" void kernel_launch(void* const* d_in, const int* in_sizes, int n_in,
                              void* d_out, int out_size, void* d_ws, size_t ws_size,
                              hipStream_t stream)
{
    (void)in_sizes; (void)n_in; (void)out_size; (void)ws_size;
    const float* x  = (const float*)d_in[0];
    const float* Wk = (const float*)d_in[1];
    const float* Wq = (const float*)d_in[2];
    const float* Wv = (const float*)d_in[3];
    float* out = (float*)d_out;

    const size_t M1 = (size_t)1024 * 1024;
    ushort* ws  = (ushort*)d_ws;
    ushort* xb  = ws;                      // 8M elems
    ushort* Tb  = xb  + 8 * M1;            // 8M
    ushort* Vt  = Tb  + 8 * M1;            // 8M (4 x [1024][2048])
    ushort* Sb  = Vt  + 8 * M1;            // 16M (4 x [2048][2048])
    ushort* Wkt = Sb  + 16 * M1;           // 1M
    ushort* Wqt = Wkt + M1;                // 1M
    ushort* Wvb = Wqt + M1;                // 1M
    ushort* Mtr = Wvb + M1;                // 1M
    float*  rsum = (float*)(Mtr + M1);     // 4*9*2048 fp32 = 294 KB

    // 0) fused conversions (x, Wv straight; Wk, Wq transposed)
    cvt_all<<<6656, 256, 0, stream>>>(x, Wk, Wq, Wv, xb, Wvb, Wkt, Wqt);
    // 1) M = (Wq^T Wk)/32 stored transposed
    m_gemm<<<dim3(8, 8), 256, 0, stream>>>(Wkt, Wqt, Mtr);
    // 2) T = x@M (z=0), V^T (z=1); 256 blocks = 1/CU
    tv_gemm8<<<dim3(32, 4, 2), 512, 0, stream>>>(xb, Mtr, Wvb, Tb, Vt);
    // 3) scores -> exp(s) with causal mask + partial row-sums
    scores_gemm8<<<dim3(36, 4), 512, 0, stream>>>(Tb, xb, Sb, rsum);
    // 4) O = P @ V with fused normalize, balanced paired row-tiles
    pv_pair<<<dim3(8, 8, 4), 512, 0, stream>>>(Sb, Vt, rsum, out);
}

// Round 12
// 146.454 us; speedup vs baseline: 1.1605x; 1.1605x over previous
//
#include <hip/hip_runtime.h>

typedef __attribute__((ext_vector_type(8))) short bf16x8;
typedef __attribute__((ext_vector_type(4))) float f32x4;
typedef __attribute__((ext_vector_type(4))) unsigned short u16x4;
typedef __attribute__((ext_vector_type(8))) unsigned short u16x8;

#define MFMA16(a, b, c) __builtin_amdgcn_mfma_f32_16x16x32_bf16((a), (b), (c), 0, 0, 0)

__device__ __forceinline__ ushort f2bf(float f) {
    unsigned u = __float_as_uint(f);
    unsigned r = (u + 0x7FFFu + ((u >> 16) & 1u)) >> 16;
    return (ushort)r;
}
__device__ __forceinline__ float bf2f(ushort s) {
    return __uint_as_float(((unsigned)s) << 16);
}

// async global->LDS, 16B per lane. LDS dest is wave-uniform base + lane*16.
__device__ __forceinline__ void async16(const ushort* g, ushort* l) {
    __builtin_amdgcn_global_load_lds(
        (const __attribute__((address_space(1))) unsigned*)g,
        (__attribute__((address_space(3))) unsigned*)l, 16, 0, 0);
}

#define SBAR()  __builtin_amdgcn_s_barrier()
#define SCHED() __builtin_amdgcn_sched_barrier(0)

// ---------------------------------------------------------------------------
// Kernel 0: fused conversions.
// blocks [0,4608): straight fp32->bf16 of x and Wv.
// blocks [4608,6656): 32x32 transpose-convert of Wk (z=0) and Wq (z=1).
// ---------------------------------------------------------------------------
__global__ __launch_bounds__(256) void cvt_all(
    const float* __restrict__ x,  const float* __restrict__ wk,
    const float* __restrict__ wq, const float* __restrict__ wv,
    ushort* __restrict__ xb,  ushort* __restrict__ wvb,
    ushort* __restrict__ wkt, ushort* __restrict__ wqt)
{
    __shared__ float t[32][33];
    int bx = blockIdx.x;
    if (bx < 4608) {
        const size_t XN = (size_t)8192 * 1024;
        size_t idx = ((size_t)bx * 256 + threadIdx.x) * 8;
        const float* s;
        ushort* d;
        if (idx < XN) { s = x + idx; d = xb + idx; }
        else          { s = wv + (idx - XN); d = wvb + (idx - XN); }
        float4 a = *(const float4*)s;
        float4 b = *(const float4*)(s + 4);
        u16x8 p;
        p[0] = f2bf(a.x); p[1] = f2bf(a.y); p[2] = f2bf(a.z); p[3] = f2bf(a.w);
        p[4] = f2bf(b.x); p[5] = f2bf(b.y); p[6] = f2bf(b.z); p[7] = f2bf(b.w);
        *(u16x8*)d = p;
    } else {
        bx -= 4608;
        const int z  = bx >> 10;
        const int tb = bx & 1023;
        const int e0 = (tb & 31) * 32, d0 = (tb >> 5) * 32;
        const float* src = z ? wq : wk;
        ushort*      dst = z ? wqt : wkt;
        const int tx = threadIdx.x & 31, ty = threadIdx.x >> 5;
#pragma unroll
        for (int r = 0; r < 4; ++r)
            t[ty + 8 * r][tx] = src[(size_t)(e0 + ty + 8 * r) * 1024 + d0 + tx];
        __syncthreads();
#pragma unroll
        for (int r = 0; r < 4; ++r)
            dst[(size_t)(d0 + ty + 8 * r) * 1024 + e0 + tx] = f2bf(t[tx][ty + 8 * r]);
    }
}

// ---------------------------------------------------------------------------
// 2-phase 128x128 core (kept for m_gemm). 256 threads.
// ---------------------------------------------------------------------------
__device__ __forceinline__ void mma_tile(
    const ushort* __restrict__ A, int lda, int abase,
    const ushort* __restrict__ B, int ldb, int bbase,
    int ktiles,
    ushort* As, ushort* Bs, f32x4 (&acc)[4][4])
{
    const int tid  = threadIdx.x;
    const int lane = tid & 63, wid = tid >> 6;
    const int wr = wid >> 1, wc = wid & 1;
    const int lrow = lane & 15, kgrp = lane >> 4;
    const int ci = lane >> 3;
    const int cc = (lane & 7) * 8;

#pragma unroll
    for (int m = 0; m < 4; ++m)
#pragma unroll
        for (int n = 0; n < 4; ++n) acc[m][n] = (f32x4){0.f, 0.f, 0.f, 0.f};

    for (int kt = 0; kt < ktiles; ++kt) {
        const int k0 = kt * 64;
#pragma unroll
        for (int i = 0; i < 4; ++i) {
            const int r = (wid * 4 + i) * 8 + ci;
            async16(&A[(size_t)(abase + r) * lda + k0 + cc], &As[(wid * 4 + i) * 512]);
            async16(&B[(size_t)(bbase + r) * ldb + k0 + cc], &Bs[(wid * 4 + i) * 512]);
        }
        __syncthreads();
#pragma unroll
        for (int kk = 0; kk < 2; ++kk) {
            bf16x8 af[4], bfr[4];
#pragma unroll
            for (int m = 0; m < 4; ++m)
                af[m] = *(const bf16x8*)&As[(wr * 64 + m * 16 + lrow) * 64 + kk * 32 + kgrp * 8];
#pragma unroll
            for (int n = 0; n < 4; ++n)
                bfr[n] = *(const bf16x8*)&Bs[(wc * 64 + n * 16 + lrow) * 64 + kk * 32 + kgrp * 8];
#pragma unroll
            for (int m = 0; m < 4; ++m)
#pragma unroll
                for (int n = 0; n < 4; ++n)
                    acc[m][n] = MFMA16(af[m], bfr[n], acc[m][n]);
        }
        __syncthreads();
    }
}

// ---------------------------------------------------------------------------
// 8-phase 256x256 core (tv, scores). 512 threads = 8 waves (2x4).
// LDS per operand: [2 buf][256 rows][64 elems] (128-B rows), 16-B-granule
// XOR swizzle phys = logical ^ (row&7) (PROVEN 0-conflict, round 10).
// Staged via pre-swizzled GLOBAL source granule (linear global_load_lds dest).
// Stage map: P1: B(t+1) lo, P2: B(t+1) hi, P4: A(t+2) lo+hi, vmcnt(4).
// ONE barrier per phase (post-MFMA barrier removed). Safety ledger:
//  - stage B(t+1)[P1/P2] targets B[(t+1)&1], last read (t-1).P4 -> >=2
//    barriers before the stage issues.
//  - stage A(t+2)[P4] targets A[t&1], last read t.P3 (kk1) -> separated by
//    P3's barrier.
//  - within every window, reads and stage touch disjoint slots.
//  - P4's vmcnt(4)+SBAR still collectively guarantees tile t+1 resident
//    before t+1.P1's reads (per-wave vmcnt + barrier = all-waves guarantee).
// ---------------------------------------------------------------------------
__device__ __forceinline__ void mma256(
    const ushort* __restrict__ A, int lda, int abase,
    const ushort* __restrict__ B, int ldb, int bbase,
    int NT, ushort* As, ushort* Bs, f32x4 (&acc)[8][4])
{
    const int tid  = threadIdx.x;
    const int lane = tid & 63, w = tid >> 6;
    const int wr = w >> 2, wc = w & 3;
    const int lrow = lane & 15, kgrp = lane >> 4;
    const int sgl  = ((lane & 7) ^ ((lane >> 3) & 7)) * 8;  // pre-swizzled src granule
    const int srow = lane >> 3;                             // row within 8-row chunk

    // stage 128 rows (hi half or lo half) of one operand for K-tile t.
    auto stage = [&](int t, int isB, int hi) {
        const ushort* src = isB ? B : A;
        const int ld = isB ? ldb : lda;
        const int rb = isB ? bbase : abase;
        ushort* buf = (isB ? Bs : As) + (size_t)(t & 1) * 16384;
#pragma unroll
        for (int i = 0; i < 2; ++i) {
            const int r = hi * 128 + (w * 2 + i) * 8 + srow;
            async16(&src[(size_t)(rb + r) * ld + t * 64 + sgl],
                    buf + (size_t)(hi * 128 + (w * 2 + i) * 8) * 64 + lane * 8);
        }
    };

#pragma unroll
    for (int m = 0; m < 8; ++m)
#pragma unroll
        for (int n = 0; n < 4; ++n) acc[m][n] = (f32x4){0.f, 0.f, 0.f, 0.f};

    // prologue: tile 0 complete (A lo/hi, B lo/hi), then tile 1's A chunks
    stage(0, 0, 0); stage(0, 0, 1); stage(0, 1, 0); stage(0, 1, 1);
    if (NT > 1) {
        stage(1, 0, 0); stage(1, 0, 1);
        asm volatile("s_waitcnt vmcnt(4)" ::: "memory");   // tile 0 resident
    } else {
        asm volatile("s_waitcnt vmcnt(0)" ::: "memory");
    }
    SCHED();
    SBAR();
    SCHED();

    const int sw = lrow & 7;   // row-derived XOR for frag reads

    for (int t = 0; t < NT; ++t) {
        ushort* Ab = As + (size_t)(t & 1) * 16384;
        ushort* Bb = Bs + (size_t)(t & 1) * 16384;
        bf16x8 af[8], bfr[2];

        // ---- P1: (kk0, n0-1); stage B(t+1) lo ----
        {
            const int g = (kgrp ^ sw) * 8;
#pragma unroll
            for (int m = 0; m < 8; ++m)
                af[m] = *(const bf16x8*)&Ab[(wr * 128 + m * 16 + lrow) * 64 + g];
#pragma unroll
            for (int n = 0; n < 2; ++n)
                bfr[n] = *(const bf16x8*)&Bb[(wc * 64 + n * 16 + lrow) * 64 + g];
        }
        if (t + 1 < NT) stage(t + 1, 1, 0);
        SBAR(); SCHED();
        __builtin_amdgcn_s_setprio(1);
#pragma unroll
        for (int m = 0; m < 8; ++m) {
            acc[m][0] = MFMA16(af[m], bfr[0], acc[m][0]);
            acc[m][1] = MFMA16(af[m], bfr[1], acc[m][1]);
        }
        __builtin_amdgcn_s_setprio(0);

        // ---- P2: (kk0, n2-3); stage B(t+1) hi ----
        {
            const int g = (kgrp ^ sw) * 8;
#pragma unroll
            for (int n = 0; n < 2; ++n)
                bfr[n] = *(const bf16x8*)&Bb[(wc * 64 + (2 + n) * 16 + lrow) * 64 + g];
        }
        if (t + 1 < NT) stage(t + 1, 1, 1);
        SBAR(); SCHED();
        __builtin_amdgcn_s_setprio(1);
#pragma unroll
        for (int m = 0; m < 8; ++m) {
            acc[m][2] = MFMA16(af[m], bfr[0], acc[m][2]);
            acc[m][3] = MFMA16(af[m], bfr[1], acc[m][3]);
        }
        __builtin_amdgcn_s_setprio(0);

        // ---- P3: (kk1, n0-1) ----
        {
            const int g = ((4 + kgrp) ^ sw) * 8;
#pragma unroll
            for (int m = 0; m < 8; ++m)
                af[m] = *(const bf16x8*)&Ab[(wr * 128 + m * 16 + lrow) * 64 + g];
#pragma unroll
            for (int n = 0; n < 2; ++n)
                bfr[n] = *(const bf16x8*)&Bb[(wc * 64 + n * 16 + lrow) * 64 + g];
        }
        SBAR(); SCHED();
        __builtin_amdgcn_s_setprio(1);
#pragma unroll
        for (int m = 0; m < 8; ++m) {
            acc[m][0] = MFMA16(af[m], bfr[0], acc[m][0]);
            acc[m][1] = MFMA16(af[m], bfr[1], acc[m][1]);
        }
        __builtin_amdgcn_s_setprio(0);

        // ---- P4: (kk1, n2-3); stage A(t+2) lo+hi + counted wait ----
        {
            const int g = ((4 + kgrp) ^ sw) * 8;
#pragma unroll
            for (int n = 0; n < 2; ++n)
                bfr[n] = *(const bf16x8*)&Bb[(wc * 64 + (2 + n) * 16 + lrow) * 64 + g];
        }
        if (t + 2 < NT) {
            stage(t + 2, 0, 0); stage(t + 2, 0, 1);
            asm volatile("s_waitcnt vmcnt(4)" ::: "memory");   // tile t+1 resident
        } else if (t + 1 < NT) {
            asm volatile("s_waitcnt vmcnt(0)" ::: "memory");
        }
        SCHED();
        SBAR(); SCHED();
        __builtin_amdgcn_s_setprio(1);
#pragma unroll
        for (int m = 0; m < 8; ++m) {
            acc[m][2] = MFMA16(af[m], bfr[0], acc[m][2]);
            acc[m][3] = MFMA16(af[m], bfr[1], acc[m][3]);
        }
        __builtin_amdgcn_s_setprio(0);
    }
}

// ---------------------------------------------------------------------------
// Kernel 1: Mtr[f][d] = (sum_e Wkt[f][e] * Wqt[d][e]) / 32  (scale folded).
// ---------------------------------------------------------------------------
__global__ __launch_bounds__(256) void m_gemm(
    const ushort* __restrict__ Wkt, const ushort* __restrict__ Wqt,
    ushort* __restrict__ Mtr)
{
    __shared__ ushort As[128 * 64];
    __shared__ ushort Bs[128 * 64];
    const int fbase = blockIdx.x * 128;
    const int dbase = blockIdx.y * 128;

    f32x4 acc[4][4];
    mma_tile(Wkt, 1024, fbase, Wqt, 1024, dbase, 16, As, Bs, acc);

    const int lane = threadIdx.x & 63, wid = threadIdx.x >> 6;
    const int wr = wid >> 1, wc = wid & 1;
    const int lrow = lane & 15, kgrp = lane >> 4;
#pragma unroll
    for (int m = 0; m < 4; ++m)
#pragma unroll
        for (int n = 0; n < 4; ++n)
#pragma unroll
            for (int r = 0; r < 4; ++r) {
                const int gf = fbase + wr * 64 + m * 16 + kgrp * 4 + r;
                const int gd = dbase + wc * 64 + n * 16 + lrow;
                Mtr[(size_t)gf * 1024 + gd] = f2bf(acc[m][n][r] * 0.03125f);
            }
}

// ---------------------------------------------------------------------------
// Kernel 2: 8-phase. z=0: T = xb @ Mtr^T -> Tb row-major. z=1: V -> Vt transposed.
// ---------------------------------------------------------------------------
__global__ __launch_bounds__(512, 2) void tv_gemm8(
    const ushort* __restrict__ xb, const ushort* __restrict__ Mtr,
    const ushort* __restrict__ Wvb,
    ushort* __restrict__ Tb, ushort* __restrict__ Vt)
{
    __shared__ ushort As[2 * 16384];
    __shared__ ushort Bs[2 * 16384];

    const int z = blockIdx.z;
    const ushort* Bmat = z ? Wvb : Mtr;
    const int mbase = blockIdx.x * 256;
    const int nbase = blockIdx.y * 256;

    f32x4 acc[8][4];
    mma256(xb, 1024, mbase, Bmat, 1024, nbase, 16, As, Bs, acc);

    const int lane = threadIdx.x & 63, w = threadIdx.x >> 6;
    const int wr = w >> 2, wc = w & 3;
    const int lrow = lane & 15, kgrp = lane >> 4;

    if (z == 1) {
        const int b  = mbase >> 11;
        const int s0 = mbase & 2047;
        ushort* VtB = Vt + (size_t)b * 1024 * 2048;
#pragma unroll
        for (int m = 0; m < 8; ++m)
#pragma unroll
            for (int n = 0; n < 4; ++n) {
                u16x4 pk;
#pragma unroll
                for (int r = 0; r < 4; ++r) pk[r] = f2bf(acc[m][n][r]);
                const int d = nbase + wc * 64 + n * 16 + lrow;
                const int s = s0 + wr * 128 + m * 16 + kgrp * 4;
                *(u16x4*)&VtB[(size_t)d * 2048 + s] = pk;
            }
    } else {
#pragma unroll
        for (int m = 0; m < 8; ++m)
#pragma unroll
            for (int n = 0; n < 4; ++n)
#pragma unroll
                for (int r = 0; r < 4; ++r) {
                    const int gr = mbase + wr * 128 + m * 16 + kgrp * 4 + r;
                    const int gc = nbase + wc * 64 + n * 16 + lrow;
                    Tb[(size_t)gr * 1024 + gc] = f2bf(acc[m][n][r]);
                }
    }
}

// ---------------------------------------------------------------------------
// Kernel 3: 8-phase scores, lower-tri 256-tiles. Stores UNNORMALIZED
// p = exp(s) with causal mask, AND writes per-(row, jt) partial row-sums
// rsum[b][jt][row] (exactly one writer each -> deterministic).
// ---------------------------------------------------------------------------
__global__ __launch_bounds__(512, 2) void scores_gemm8(
    const ushort* __restrict__ Tb, const ushort* __restrict__ xb,
    ushort* __restrict__ Sall, float* __restrict__ rsum)
{
    __shared__ ushort As[2 * 16384];
    __shared__ ushort Bs[2 * 16384];

    ushort* S = Sall + (size_t)blockIdx.y * 2048 * 2048;
    const int rb = blockIdx.y * 2048;

    int t = blockIdx.x;
    int it = (int)((sqrtf(8.0f * (float)t + 1.0f) - 1.0f) * 0.5f);
    while ((it + 1) * (it + 2) / 2 <= t) ++it;
    while (it * (it + 1) / 2 > t) --it;
    const int jt = t - it * (it + 1) / 2;
    const int ibase = it * 256, jbase = jt * 256;
    const bool diag = (it == jt);

    f32x4 acc[8][4];
    mma256(Tb, 1024, rb + ibase, xb, 1024, rb + jbase, 16, As, Bs, acc);

    const int tid = threadIdx.x;
    const int lane = tid & 63, w = tid >> 6;
    const int wr = w >> 2, wc = w & 3;
    const int lrow = lane & 15, kgrp = lane >> 4;

    float prs[8][4];
#pragma unroll
    for (int m = 0; m < 8; ++m)
#pragma unroll
        for (int r = 0; r < 4; ++r) prs[m][r] = 0.f;

#pragma unroll
    for (int m = 0; m < 8; ++m)
#pragma unroll
        for (int n = 0; n < 4; ++n)
#pragma unroll
            for (int r = 0; r < 4; ++r) {
                const int gi = ibase + wr * 128 + m * 16 + kgrp * 4 + r;
                const int gj = jbase + wc * 64 + n * 16 + lrow;
                float p = __expf(acc[m][n][r]);
                if (diag && gj > gi) p = 0.f;
                S[(size_t)gi * 2048 + gj] = f2bf(p);
                prs[m][r] += p;
            }

    // reduce partial sums over lrow (16 lanes), stash per-wave slice in LDS
    float* psum = (float*)As;   // [2 wr][4 wc][128 rows] = 4 KB (As is dead)
#pragma unroll
    for (int m = 0; m < 8; ++m)
#pragma unroll
        for (int r = 0; r < 4; ++r) {
            float v = prs[m][r];
            v += __shfl_xor(v, 1);
            v += __shfl_xor(v, 2);
            v += __shfl_xor(v, 4);
            v += __shfl_xor(v, 8);
            prs[m][r] = v;
        }
    if (lrow == 0) {
#pragma unroll
        for (int m = 0; m < 8; ++m)
#pragma unroll
            for (int r = 0; r < 4; ++r)
                psum[(wr * 4 + wc) * 128 + m * 16 + kgrp * 4 + r] = prs[m][r];
    }
    __syncthreads();
    if (tid < 256) {
        const int half = tid >> 7, rr = tid & 127;
        float s4 = psum[(half * 4 + 0) * 128 + rr] + psum[(half * 4 + 1) * 128 + rr]
                 + psum[(half * 4 + 2) * 128 + rr] + psum[(half * 4 + 3) * 128 + rr];
        rsum[(size_t)(blockIdx.y * 9 + jt) * 2048 + ibase + tid] = s4;
    }
}

// ---------------------------------------------------------------------------
// PV sub-GEMM: O-rows [it*128, +128) x cols [nbase, +128). Fat single-phase,
// 3-deep prefetch (3 LDS buffers). stage() = 4 loads/thread. Ledger: at the
// in-loop wait, outstanding = {t+1,t+2,t+3} x 4 = 12 -> vmcnt(8) completes
// t+1. Tails: t+3==NT -> vmcnt(4); t+2==NT -> vmcnt(0).
// XOR-16B swizzled LDS. Row normalization from precomputed rsum partials.
// ---------------------------------------------------------------------------
__device__ __forceinline__ void pv_sub(
    const ushort* __restrict__ P, const ushort* __restrict__ Vt,
    float* __restrict__ O, const float* __restrict__ rsb,
    int it, int nbase, ushort* As, ushort* Bs, float* rs)
{
    const int tid  = threadIdx.x;
    const int lane = tid & 63, w = tid >> 6;
    const int wr = w >> 2, wc = w & 3;
    const int lrow = lane & 15, kgrp = lane >> 4;
    const int srow = lane >> 3;
    const int sc16 = (lane & 7) ^ srow;
    const int pbase = it * 128;
    const int NT = 2 * (it + 1);
    const int jtmax = it >> 1;

    auto stage = [&](int t, int slot) {
        ushort* dA = As + (size_t)slot * 8192;
        ushort* dB = Bs + (size_t)slot * 8192;
#pragma unroll
        for (int i = 0; i < 2; ++i) {
            const int rr = (i * 8 + w) * 8 + srow;
            async16(&P [(size_t)(pbase + rr) * 2048 + t * 64 + sc16 * 8],
                    dA + ((i * 8 + w) * 64 + lane) * 8);
            async16(&Vt[(size_t)(nbase + rr) * 2048 + t * 64 + sc16 * 8],
                    dB + ((i * 8 + w) * 64 + lane) * 8);
        }
    };

    // precompute row normalizers (<= 9 partials per row)
    if (tid < 128) {
        float s = 0.f;
        for (int j = 0; j <= jtmax; ++j)
            s += rsb[(size_t)j * 2048 + pbase + tid];
        rs[tid] = 1.0f / s;
    }

    f32x4 acc[4][2];
#pragma unroll
    for (int m = 0; m < 4; ++m)
#pragma unroll
        for (int n = 0; n < 2; ++n) acc[m][n] = (f32x4){0.f, 0.f, 0.f, 0.f};

    stage(0, 0);
    if (NT > 2) {
        stage(1, 1); stage(2, 2);
        asm volatile("s_waitcnt vmcnt(8)" ::: "memory");   // tile 0 resident
    } else {   // NT == 2
        stage(1, 1);
        asm volatile("s_waitcnt vmcnt(4)" ::: "memory");   // tile 0 resident
    }
    SCHED();
    SBAR(); SCHED();

    int bi = 0;
    for (int t = 0; t < NT; ++t) {
        const ushort* Ab = As + (size_t)bi * 8192;
        const ushort* Bb = Bs + (size_t)bi * 8192;
        bf16x8 af[2][4], bq[2][2];
#pragma unroll
        for (int kk = 0; kk < 2; ++kk) {
            const int p16 = (kk * 4 + kgrp) ^ (lrow & 7);
#pragma unroll
            for (int m = 0; m < 4; ++m) {
                const int row = wr * 64 + m * 16 + lrow;
                af[kk][m] = *(const bf16x8*)&Ab[row * 64 + p16 * 8];
            }
#pragma unroll
            for (int n = 0; n < 2; ++n) {
                const int row = wc * 32 + n * 16 + lrow;
                bq[kk][n] = *(const bf16x8*)&Bb[row * 64 + p16 * 8];
            }
        }
        asm volatile("s_waitcnt lgkmcnt(0)" ::: "memory");
        SCHED();
        SBAR(); SCHED();                   // buf[bi] fully read -> released
        if (t + 3 < NT) {
            stage(t + 3, bi);
            asm volatile("s_waitcnt vmcnt(8)" ::: "memory");  // t+1 complete
        } else if (t + 3 == NT) {
            asm volatile("s_waitcnt vmcnt(4)" ::: "memory");  // t+1 complete
        } else if (t + 2 == NT) {
            asm volatile("s_waitcnt vmcnt(0)" ::: "memory");  // t+1 complete
        }
        SCHED();
        SBAR(); SCHED();                   // t+1 resident for all waves
        __builtin_amdgcn_s_setprio(1);
#pragma unroll
        for (int kk = 0; kk < 2; ++kk)
#pragma unroll
            for (int m = 0; m < 4; ++m) {
                acc[m][0] = MFMA16(af[kk][m], bq[kk][0], acc[m][0]);
                acc[m][1] = MFMA16(af[kk][m], bq[kk][1], acc[m][1]);
            }
        __builtin_amdgcn_s_setprio(0);
        bi = (bi == 2) ? 0 : bi + 1;
    }

    __syncthreads();   // rs[] ready (written pre-loop by tid<128)

#pragma unroll
    for (int m = 0; m < 4; ++m)
#pragma unroll
        for (int r = 0; r < 4; ++r) {
            const int ri = wr * 64 + m * 16 + kgrp * 4 + r;
            const float inv = rs[ri];
            const int gi = pbase + ri;
#pragma unroll
            for (int n = 0; n < 2; ++n) {
                const int gc = nbase + wc * 32 + n * 16 + lrow;
                O[(size_t)gi * 1024 + gc] = acc[m][n][r] * inv;
            }
        }
    __syncthreads();
}

// ---------------------------------------------------------------------------
// Kernel 4: O = P @ V with fused normalize. Paired row-tiles (15-bx, bx):
// every block exactly 34 k-tiles. grid (8, 8, 4) = 256 blocks = 1/CU.
// ---------------------------------------------------------------------------
__global__ __launch_bounds__(512, 2) void pv_pair(
    const ushort* __restrict__ Pall, const ushort* __restrict__ Vtall,
    const float* __restrict__ rsum, float* __restrict__ Oall)
{
    __shared__ ushort As[3 * 8192];   // 48 KiB
    __shared__ ushort Bs[3 * 8192];   // 48 KiB
    __shared__ float rs[128];

    const ushort* P  = Pall  + (size_t)blockIdx.z * 2048 * 2048;
    const ushort* Vt = Vtall + (size_t)blockIdx.z * 1024 * 2048;
    const float* rsb = rsum  + (size_t)blockIdx.z * 9 * 2048;
    float*        O  = Oall  + (size_t)blockIdx.z * 2048 * 1024;
    const int nbase = blockIdx.y * 128;

    pv_sub(P, Vt, O, rsb, 15 - (int)blockIdx.x, nbase, As, Bs, rs);
    pv_sub(P, Vt, O, rsb, (int)blockIdx.x,      nbase, As, Bs, rs);
}

// ---------------------------------------------------------------------------
extern "C" void kernel_launch(void* const* d_in, const int* in_sizes, int n_in,
                              void* d_out, int out_size, void* d_ws, size_t ws_size,
                              hipStream_t stream)
{
    (void)in_sizes; (void)n_in; (void)out_size; (void)ws_size;
    const float* x  = (const float*)d_in[0];
    const float* Wk = (const float*)d_in[1];
    const float* Wq = (const float*)d_in[2];
    const float* Wv = (const float*)d_in[3];
    float* out = (float*)d_out;

    const size_t M1 = (size_t)1024 * 1024;
    ushort* ws  = (ushort*)d_ws;
    ushort* xb  = ws;                      // 8M elems
    ushort* Tb  = xb  + 8 * M1;            // 8M
    ushort* Vt  = Tb  + 8 * M1;            // 8M (4 x [1024][2048])
    ushort* Sb  = Vt  + 8 * M1;            // 16M (4 x [2048][2048])
    ushort* Wkt = Sb  + 16 * M1;           // 1M
    ushort* Wqt = Wkt + M1;                // 1M
    ushort* Wvb = Wqt + M1;                // 1M
    ushort* Mtr = Wvb + M1;                // 1M
    float*  rsum = (float*)(Mtr + M1);     // 4*9*2048 fp32 = 294 KB

    // 0) fused conversions (x, Wv straight; Wk, Wq transposed)
    cvt_all<<<6656, 256, 0, stream>>>(x, Wk, Wq, Wv, xb, Wvb, Wkt, Wqt);
    // 1) M = (Wq^T Wk)/32 stored transposed
    m_gemm<<<dim3(8, 8), 256, 0, stream>>>(Wkt, Wqt, Mtr);
    // 2) T = x@M (z=0), V^T (z=1); 256 blocks = 1/CU
    tv_gemm8<<<dim3(32, 4, 2), 512, 0, stream>>>(xb, Mtr, Wvb, Tb, Vt);
    // 3) scores -> exp(s) with causal mask + partial row-sums
    scores_gemm8<<<dim3(36, 4), 512, 0, stream>>>(Tb, xb, Sb, rsum);
    // 4) O = P @ V with fused normalize, balanced paired row-tiles
    pv_pair<<<dim3(8, 8, 4), 512, 0, stream>>>(Sb, Vt, rsum, out);
}

// Round 13
// 144.036 us; speedup vs baseline: 1.1799x; 1.0168x over previous
//
#include <hip/hip_runtime.h>

typedef __attribute__((ext_vector_type(8))) short bf16x8;
typedef __attribute__((ext_vector_type(4))) float f32x4;
typedef __attribute__((ext_vector_type(4))) unsigned short u16x4;
typedef __attribute__((ext_vector_type(8))) unsigned short u16x8;

#define MFMA16(a, b, c) __builtin_amdgcn_mfma_f32_16x16x32_bf16((a), (b), (c), 0, 0, 0)

__device__ __forceinline__ ushort f2bf(float f) {
    unsigned u = __float_as_uint(f);
    unsigned r = (u + 0x7FFFu + ((u >> 16) & 1u)) >> 16;
    return (ushort)r;
}
__device__ __forceinline__ float bf2f(ushort s) {
    return __uint_as_float(((unsigned)s) << 16);
}

// async global->LDS, 16B per lane. LDS dest is wave-uniform base + lane*16.
__device__ __forceinline__ void async16(const ushort* g, ushort* l) {
    __builtin_amdgcn_global_load_lds(
        (const __attribute__((address_space(1))) unsigned*)g,
        (__attribute__((address_space(3))) unsigned*)l, 16, 0, 0);
}

#define SBAR()  __builtin_amdgcn_s_barrier()
#define SCHED() __builtin_amdgcn_sched_barrier(0)

// ---------------------------------------------------------------------------
// Kernel 0: fused conversions.
// blocks [0,4608): straight fp32->bf16 of x and Wv.
// blocks [4608,6656): 32x32 transpose-convert of Wk (z=0) and Wq (z=1).
// ---------------------------------------------------------------------------
__global__ __launch_bounds__(256) void cvt_all(
    const float* __restrict__ x,  const float* __restrict__ wk,
    const float* __restrict__ wq, const float* __restrict__ wv,
    ushort* __restrict__ xb,  ushort* __restrict__ wvb,
    ushort* __restrict__ wkt, ushort* __restrict__ wqt)
{
    __shared__ float t[32][33];
    int bx = blockIdx.x;
    if (bx < 4608) {
        const size_t XN = (size_t)8192 * 1024;
        size_t idx = ((size_t)bx * 256 + threadIdx.x) * 8;
        const float* s;
        ushort* d;
        if (idx < XN) { s = x + idx; d = xb + idx; }
        else          { s = wv + (idx - XN); d = wvb + (idx - XN); }
        float4 a = *(const float4*)s;
        float4 b = *(const float4*)(s + 4);
        u16x8 p;
        p[0] = f2bf(a.x); p[1] = f2bf(a.y); p[2] = f2bf(a.z); p[3] = f2bf(a.w);
        p[4] = f2bf(b.x); p[5] = f2bf(b.y); p[6] = f2bf(b.z); p[7] = f2bf(b.w);
        *(u16x8*)d = p;
    } else {
        bx -= 4608;
        const int z  = bx >> 10;
        const int tb = bx & 1023;
        const int e0 = (tb & 31) * 32, d0 = (tb >> 5) * 32;
        const float* src = z ? wq : wk;
        ushort*      dst = z ? wqt : wkt;
        const int tx = threadIdx.x & 31, ty = threadIdx.x >> 5;
#pragma unroll
        for (int r = 0; r < 4; ++r)
            t[ty + 8 * r][tx] = src[(size_t)(e0 + ty + 8 * r) * 1024 + d0 + tx];
        __syncthreads();
#pragma unroll
        for (int r = 0; r < 4; ++r)
            dst[(size_t)(d0 + ty + 8 * r) * 1024 + e0 + tx] = f2bf(t[tx][ty + 8 * r]);
    }
}

// ---------------------------------------------------------------------------
// 2-phase 128x128 core (kept for m_gemm). 256 threads.
// ---------------------------------------------------------------------------
__device__ __forceinline__ void mma_tile(
    const ushort* __restrict__ A, int lda, int abase,
    const ushort* __restrict__ B, int ldb, int bbase,
    int ktiles,
    ushort* As, ushort* Bs, f32x4 (&acc)[4][4])
{
    const int tid  = threadIdx.x;
    const int lane = tid & 63, wid = tid >> 6;
    const int wr = wid >> 1, wc = wid & 1;
    const int lrow = lane & 15, kgrp = lane >> 4;
    const int ci = lane >> 3;
    const int cc = (lane & 7) * 8;

#pragma unroll
    for (int m = 0; m < 4; ++m)
#pragma unroll
        for (int n = 0; n < 4; ++n) acc[m][n] = (f32x4){0.f, 0.f, 0.f, 0.f};

    for (int kt = 0; kt < ktiles; ++kt) {
        const int k0 = kt * 64;
#pragma unroll
        for (int i = 0; i < 4; ++i) {
            const int r = (wid * 4 + i) * 8 + ci;
            async16(&A[(size_t)(abase + r) * lda + k0 + cc], &As[(wid * 4 + i) * 512]);
            async16(&B[(size_t)(bbase + r) * ldb + k0 + cc], &Bs[(wid * 4 + i) * 512]);
        }
        __syncthreads();
#pragma unroll
        for (int kk = 0; kk < 2; ++kk) {
            bf16x8 af[4], bfr[4];
#pragma unroll
            for (int m = 0; m < 4; ++m)
                af[m] = *(const bf16x8*)&As[(wr * 64 + m * 16 + lrow) * 64 + kk * 32 + kgrp * 8];
#pragma unroll
            for (int n = 0; n < 4; ++n)
                bfr[n] = *(const bf16x8*)&Bs[(wc * 64 + n * 16 + lrow) * 64 + kk * 32 + kgrp * 8];
#pragma unroll
            for (int m = 0; m < 4; ++m)
#pragma unroll
                for (int n = 0; n < 4; ++n)
                    acc[m][n] = MFMA16(af[m], bfr[n], acc[m][n]);
        }
        __syncthreads();
    }
}

// ---------------------------------------------------------------------------
// 8-phase 256x256 core (tv, scores). 512 threads = 8 waves (2x4).
// LDS per operand: [2 buf][256 rows][64 elems] (128-B rows), 16-B-granule
// XOR swizzle phys = logical ^ (row&7) (proven 0-conflict, round 10).
// ONE barrier per phase (round 12); stage map P1: B(t+1) lo, P2: B(t+1) hi,
// P4: A(t+2) lo+hi + vmcnt(4).
// ---------------------------------------------------------------------------
__device__ __forceinline__ void mma256(
    const ushort* __restrict__ A, int lda, int abase,
    const ushort* __restrict__ B, int ldb, int bbase,
    int NT, ushort* As, ushort* Bs, f32x4 (&acc)[8][4])
{
    const int tid  = threadIdx.x;
    const int lane = tid & 63, w = tid >> 6;
    const int wr = w >> 2, wc = w & 3;
    const int lrow = lane & 15, kgrp = lane >> 4;
    const int sgl  = ((lane & 7) ^ ((lane >> 3) & 7)) * 8;  // pre-swizzled src granule
    const int srow = lane >> 3;                             // row within 8-row chunk

    auto stage = [&](int t, int isB, int hi) {
        const ushort* src = isB ? B : A;
        const int ld = isB ? ldb : lda;
        const int rb = isB ? bbase : abase;
        ushort* buf = (isB ? Bs : As) + (size_t)(t & 1) * 16384;
#pragma unroll
        for (int i = 0; i < 2; ++i) {
            const int r = hi * 128 + (w * 2 + i) * 8 + srow;
            async16(&src[(size_t)(rb + r) * ld + t * 64 + sgl],
                    buf + (size_t)(hi * 128 + (w * 2 + i) * 8) * 64 + lane * 8);
        }
    };

#pragma unroll
    for (int m = 0; m < 8; ++m)
#pragma unroll
        for (int n = 0; n < 4; ++n) acc[m][n] = (f32x4){0.f, 0.f, 0.f, 0.f};

    stage(0, 0, 0); stage(0, 0, 1); stage(0, 1, 0); stage(0, 1, 1);
    if (NT > 1) {
        stage(1, 0, 0); stage(1, 0, 1);
        asm volatile("s_waitcnt vmcnt(4)" ::: "memory");
    } else {
        asm volatile("s_waitcnt vmcnt(0)" ::: "memory");
    }
    SCHED();
    SBAR();
    SCHED();

    const int sw = lrow & 7;

    for (int t = 0; t < NT; ++t) {
        ushort* Ab = As + (size_t)(t & 1) * 16384;
        ushort* Bb = Bs + (size_t)(t & 1) * 16384;
        bf16x8 af[8], bfr[2];

        // ---- P1: (kk0, n0-1); stage B(t+1) lo ----
        {
            const int g = (kgrp ^ sw) * 8;
#pragma unroll
            for (int m = 0; m < 8; ++m)
                af[m] = *(const bf16x8*)&Ab[(wr * 128 + m * 16 + lrow) * 64 + g];
#pragma unroll
            for (int n = 0; n < 2; ++n)
                bfr[n] = *(const bf16x8*)&Bb[(wc * 64 + n * 16 + lrow) * 64 + g];
        }
        if (t + 1 < NT) stage(t + 1, 1, 0);
        SBAR(); SCHED();
        __builtin_amdgcn_s_setprio(1);
#pragma unroll
        for (int m = 0; m < 8; ++m) {
            acc[m][0] = MFMA16(af[m], bfr[0], acc[m][0]);
            acc[m][1] = MFMA16(af[m], bfr[1], acc[m][1]);
        }
        __builtin_amdgcn_s_setprio(0);

        // ---- P2: (kk0, n2-3); stage B(t+1) hi ----
        {
            const int g = (kgrp ^ sw) * 8;
#pragma unroll
            for (int n = 0; n < 2; ++n)
                bfr[n] = *(const bf16x8*)&Bb[(wc * 64 + (2 + n) * 16 + lrow) * 64 + g];
        }
        if (t + 1 < NT) stage(t + 1, 1, 1);
        SBAR(); SCHED();
        __builtin_amdgcn_s_setprio(1);
#pragma unroll
        for (int m = 0; m < 8; ++m) {
            acc[m][2] = MFMA16(af[m], bfr[0], acc[m][2]);
            acc[m][3] = MFMA16(af[m], bfr[1], acc[m][3]);
        }
        __builtin_amdgcn_s_setprio(0);

        // ---- P3: (kk1, n0-1) ----
        {
            const int g = ((4 + kgrp) ^ sw) * 8;
#pragma unroll
            for (int m = 0; m < 8; ++m)
                af[m] = *(const bf16x8*)&Ab[(wr * 128 + m * 16 + lrow) * 64 + g];
#pragma unroll
            for (int n = 0; n < 2; ++n)
                bfr[n] = *(const bf16x8*)&Bb[(wc * 64 + n * 16 + lrow) * 64 + g];
        }
        SBAR(); SCHED();
        __builtin_amdgcn_s_setprio(1);
#pragma unroll
        for (int m = 0; m < 8; ++m) {
            acc[m][0] = MFMA16(af[m], bfr[0], acc[m][0]);
            acc[m][1] = MFMA16(af[m], bfr[1], acc[m][1]);
        }
        __builtin_amdgcn_s_setprio(0);

        // ---- P4: (kk1, n2-3); stage A(t+2) lo+hi + counted wait ----
        {
            const int g = ((4 + kgrp) ^ sw) * 8;
#pragma unroll
            for (int n = 0; n < 2; ++n)
                bfr[n] = *(const bf16x8*)&Bb[(wc * 64 + (2 + n) * 16 + lrow) * 64 + g];
        }
        if (t + 2 < NT) {
            stage(t + 2, 0, 0); stage(t + 2, 0, 1);
            asm volatile("s_waitcnt vmcnt(4)" ::: "memory");
        } else if (t + 1 < NT) {
            asm volatile("s_waitcnt vmcnt(0)" ::: "memory");
        }
        SCHED();
        SBAR(); SCHED();
        __builtin_amdgcn_s_setprio(1);
#pragma unroll
        for (int m = 0; m < 8; ++m) {
            acc[m][2] = MFMA16(af[m], bfr[0], acc[m][2]);
            acc[m][3] = MFMA16(af[m], bfr[1], acc[m][3]);
        }
        __builtin_amdgcn_s_setprio(0);
    }
}

// ---------------------------------------------------------------------------
// Kernel 1: Mtr[f][d] = (sum_e Wkt[f][e] * Wqt[d][e]) / 32  (scale folded).
// ---------------------------------------------------------------------------
__global__ __launch_bounds__(256) void m_gemm(
    const ushort* __restrict__ Wkt, const ushort* __restrict__ Wqt,
    ushort* __restrict__ Mtr)
{
    __shared__ ushort As[128 * 64];
    __shared__ ushort Bs[128 * 64];
    const int fbase = blockIdx.x * 128;
    const int dbase = blockIdx.y * 128;

    f32x4 acc[4][4];
    mma_tile(Wkt, 1024, fbase, Wqt, 1024, dbase, 16, As, Bs, acc);

    const int lane = threadIdx.x & 63, wid = threadIdx.x >> 6;
    const int wr = wid >> 1, wc = wid & 1;
    const int lrow = lane & 15, kgrp = lane >> 4;
#pragma unroll
    for (int m = 0; m < 4; ++m)
#pragma unroll
        for (int n = 0; n < 4; ++n)
#pragma unroll
            for (int r = 0; r < 4; ++r) {
                const int gf = fbase + wr * 64 + m * 16 + kgrp * 4 + r;
                const int gd = dbase + wc * 64 + n * 16 + lrow;
                Mtr[(size_t)gf * 1024 + gd] = f2bf(acc[m][n][r] * 0.03125f);
            }
}

// ---------------------------------------------------------------------------
// Kernel 2: 8-phase. z=0: T = xb @ Mtr^T -> Tb row-major. z=1: V -> Vt transposed.
// ---------------------------------------------------------------------------
__global__ __launch_bounds__(512, 2) void tv_gemm8(
    const ushort* __restrict__ xb, const ushort* __restrict__ Mtr,
    const ushort* __restrict__ Wvb,
    ushort* __restrict__ Tb, ushort* __restrict__ Vt)
{
    __shared__ ushort As[2 * 16384];
    __shared__ ushort Bs[2 * 16384];

    const int z = blockIdx.z;
    const ushort* Bmat = z ? Wvb : Mtr;
    const int mbase = blockIdx.x * 256;
    const int nbase = blockIdx.y * 256;

    f32x4 acc[8][4];
    mma256(xb, 1024, mbase, Bmat, 1024, nbase, 16, As, Bs, acc);

    const int lane = threadIdx.x & 63, w = threadIdx.x >> 6;
    const int wr = w >> 2, wc = w & 3;
    const int lrow = lane & 15, kgrp = lane >> 4;

    if (z == 1) {
        const int b  = mbase >> 11;
        const int s0 = mbase & 2047;
        ushort* VtB = Vt + (size_t)b * 1024 * 2048;
#pragma unroll
        for (int m = 0; m < 8; ++m)
#pragma unroll
            for (int n = 0; n < 4; ++n) {
                u16x4 pk;
#pragma unroll
                for (int r = 0; r < 4; ++r) pk[r] = f2bf(acc[m][n][r]);
                const int d = nbase + wc * 64 + n * 16 + lrow;
                const int s = s0 + wr * 128 + m * 16 + kgrp * 4;
                *(u16x4*)&VtB[(size_t)d * 2048 + s] = pk;
            }
    } else {
#pragma unroll
        for (int m = 0; m < 8; ++m)
#pragma unroll
            for (int n = 0; n < 4; ++n)
#pragma unroll
                for (int r = 0; r < 4; ++r) {
                    const int gr = mbase + wr * 128 + m * 16 + kgrp * 4 + r;
                    const int gc = nbase + wc * 64 + n * 16 + lrow;
                    Tb[(size_t)gr * 1024 + gc] = f2bf(acc[m][n][r]);
                }
    }
}

// ---------------------------------------------------------------------------
// Kernel 3: 8-phase scores, lower-tri 256-tiles. Stores UNNORMALIZED
// p = exp(s) with causal mask, AND writes per-(row, jt) partial row-sums
// rsum[b][jt][row] (exactly one writer each -> deterministic).
// ---------------------------------------------------------------------------
__global__ __launch_bounds__(512, 2) void scores_gemm8(
    const ushort* __restrict__ Tb, const ushort* __restrict__ xb,
    ushort* __restrict__ Sall, float* __restrict__ rsum)
{
    __shared__ ushort As[2 * 16384];
    __shared__ ushort Bs[2 * 16384];

    ushort* S = Sall + (size_t)blockIdx.y * 2048 * 2048;
    const int rb = blockIdx.y * 2048;

    int t = blockIdx.x;
    int it = (int)((sqrtf(8.0f * (float)t + 1.0f) - 1.0f) * 0.5f);
    while ((it + 1) * (it + 2) / 2 <= t) ++it;
    while (it * (it + 1) / 2 > t) --it;
    const int jt = t - it * (it + 1) / 2;
    const int ibase = it * 256, jbase = jt * 256;
    const bool diag = (it == jt);

    f32x4 acc[8][4];
    mma256(Tb, 1024, rb + ibase, xb, 1024, rb + jbase, 16, As, Bs, acc);

    const int tid = threadIdx.x;
    const int lane = tid & 63, w = tid >> 6;
    const int wr = w >> 2, wc = w & 3;
    const int lrow = lane & 15, kgrp = lane >> 4;

    float prs[8][4];
#pragma unroll
    for (int m = 0; m < 8; ++m)
#pragma unroll
        for (int r = 0; r < 4; ++r) prs[m][r] = 0.f;

#pragma unroll
    for (int m = 0; m < 8; ++m)
#pragma unroll
        for (int n = 0; n < 4; ++n)
#pragma unroll
            for (int r = 0; r < 4; ++r) {
                const int gi = ibase + wr * 128 + m * 16 + kgrp * 4 + r;
                const int gj = jbase + wc * 64 + n * 16 + lrow;
                float p = __expf(acc[m][n][r]);
                if (diag && gj > gi) p = 0.f;
                S[(size_t)gi * 2048 + gj] = f2bf(p);
                prs[m][r] += p;
            }

    // reduce partial sums over lrow (16 lanes), stash per-wave slice in LDS
    float* psum = (float*)As;   // [2 wr][4 wc][128 rows] = 4 KB (As is dead)
#pragma unroll
    for (int m = 0; m < 8; ++m)
#pragma unroll
        for (int r = 0; r < 4; ++r) {
            float v = prs[m][r];
            v += __shfl_xor(v, 1);
            v += __shfl_xor(v, 2);
            v += __shfl_xor(v, 4);
            v += __shfl_xor(v, 8);
            prs[m][r] = v;
        }
    if (lrow == 0) {
#pragma unroll
        for (int m = 0; m < 8; ++m)
#pragma unroll
            for (int r = 0; r < 4; ++r)
                psum[(wr * 4 + wc) * 128 + m * 16 + kgrp * 4 + r] = prs[m][r];
    }
    __syncthreads();
    if (tid < 256) {
        const int half = tid >> 7, rr = tid & 127;
        float s4 = psum[(half * 4 + 0) * 128 + rr] + psum[(half * 4 + 1) * 128 + rr]
                 + psum[(half * 4 + 2) * 128 + rr] + psum[(half * 4 + 3) * 128 + rr];
        rsum[(size_t)(blockIdx.y * 9 + jt) * 2048 + ibase + tid] = s4;
    }
}

// ---------------------------------------------------------------------------
// Kernel 4: O = P @ V with fused normalize, ONE 128-row tile per block,
// 2-buffer (32 KiB x2) for 2 blocks/CU occupancy (TLP hides the stalls).
// grid (16 its heavy-first, 8 nc, 4 b) = 512 blocks = 2/CU.
// Ledger (stage = 4 loads/thread, 1-deep): prologue stage(0)+stage(1),
// vmcnt(4) -> tile 0 resident. Loop: read buf[t&1] -> lgkmcnt(0)+SBAR
// (reads done, buffer free) -> stage(t+2 -> buf[t&1]) -> vmcnt(4)
// (completes t+1, leaves t+2's 4) -> SBAR -> MFMA.
// Tails: t+2>=NT -> no stage; t+1<NT -> vmcnt(0).
// ---------------------------------------------------------------------------
__global__ __launch_bounds__(512, 4) void pv_one(
    const ushort* __restrict__ Pall, const ushort* __restrict__ Vtall,
    const float* __restrict__ rsum, float* __restrict__ Oall)
{
    __shared__ ushort As[2 * 8192];   // 32 KiB
    __shared__ ushort Bs[2 * 8192];   // 32 KiB
    __shared__ float rs[128];

    const ushort* P  = Pall  + (size_t)blockIdx.z * 2048 * 2048;
    const ushort* Vt = Vtall + (size_t)blockIdx.z * 1024 * 2048;
    const float* rsb = rsum  + (size_t)blockIdx.z * 9 * 2048;
    float*        O  = Oall  + (size_t)blockIdx.z * 2048 * 1024;
    const int nbase = blockIdx.y * 128;
    const int it    = 15 - (int)blockIdx.x;   // heavy-first

    const int tid  = threadIdx.x;
    const int lane = tid & 63, w = tid >> 6;
    const int wr = w >> 2, wc = w & 3;
    const int lrow = lane & 15, kgrp = lane >> 4;
    const int srow = lane >> 3;
    const int sc16 = (lane & 7) ^ srow;
    const int pbase = it * 128;
    const int NT = 2 * (it + 1);
    const int jtmax = it >> 1;

    auto stage = [&](int t, int slot) {
        ushort* dA = As + (size_t)slot * 8192;
        ushort* dB = Bs + (size_t)slot * 8192;
#pragma unroll
        for (int i = 0; i < 2; ++i) {
            const int rr = (i * 8 + w) * 8 + srow;
            async16(&P [(size_t)(pbase + rr) * 2048 + t * 64 + sc16 * 8],
                    dA + ((i * 8 + w) * 64 + lane) * 8);
            async16(&Vt[(size_t)(nbase + rr) * 2048 + t * 64 + sc16 * 8],
                    dB + ((i * 8 + w) * 64 + lane) * 8);
        }
    };

    // precompute row normalizers (<= 9 partials per row)
    if (tid < 128) {
        float s = 0.f;
        for (int j = 0; j <= jtmax; ++j)
            s += rsb[(size_t)j * 2048 + pbase + tid];
        rs[tid] = 1.0f / s;
    }

    f32x4 acc[4][2];
#pragma unroll
    for (int m = 0; m < 4; ++m)
#pragma unroll
        for (int n = 0; n < 2; ++n) acc[m][n] = (f32x4){0.f, 0.f, 0.f, 0.f};

    stage(0, 0);
    stage(1, 1);                               // NT >= 2 always
    asm volatile("s_waitcnt vmcnt(4)" ::: "memory");   // tile 0 resident
    SCHED();
    SBAR(); SCHED();

    for (int t = 0; t < NT; ++t) {
        const int bi = t & 1;
        const ushort* Ab = As + (size_t)bi * 8192;
        const ushort* Bb = Bs + (size_t)bi * 8192;
        bf16x8 af[2][4], bq[2][2];
#pragma unroll
        for (int kk = 0; kk < 2; ++kk) {
            const int p16 = (kk * 4 + kgrp) ^ (lrow & 7);
#pragma unroll
            for (int m = 0; m < 4; ++m) {
                const int row = wr * 64 + m * 16 + lrow;
                af[kk][m] = *(const bf16x8*)&Ab[row * 64 + p16 * 8];
            }
#pragma unroll
            for (int n = 0; n < 2; ++n) {
                const int row = wc * 32 + n * 16 + lrow;
                bq[kk][n] = *(const bf16x8*)&Bb[row * 64 + p16 * 8];
            }
        }
        asm volatile("s_waitcnt lgkmcnt(0)" ::: "memory");
        SCHED();
        SBAR(); SCHED();                   // buf[bi] fully read -> released
        if (t + 2 < NT) {
            stage(t + 2, bi);
            asm volatile("s_waitcnt vmcnt(4)" ::: "memory");  // t+1 complete
        } else if (t + 1 < NT) {
            asm volatile("s_waitcnt vmcnt(0)" ::: "memory");  // t+1 complete
        }
        SCHED();
        SBAR(); SCHED();                   // t+1 resident for all waves
        __builtin_amdgcn_s_setprio(1);
#pragma unroll
        for (int kk = 0; kk < 2; ++kk)
#pragma unroll
            for (int m = 0; m < 4; ++m) {
                acc[m][0] = MFMA16(af[kk][m], bq[kk][0], acc[m][0]);
                acc[m][1] = MFMA16(af[kk][m], bq[kk][1], acc[m][1]);
            }
        __builtin_amdgcn_s_setprio(0);
    }

    __syncthreads();   // rs[] ready

#pragma unroll
    for (int m = 0; m < 4; ++m)
#pragma unroll
        for (int r = 0; r < 4; ++r) {
            const int ri = wr * 64 + m * 16 + kgrp * 4 + r;
            const float inv = rs[ri];
            const int gi = pbase + ri;
#pragma unroll
            for (int n = 0; n < 2; ++n) {
                const int gc = nbase + wc * 32 + n * 16 + lrow;
                O[(size_t)gi * 1024 + gc] = acc[m][n][r] * inv;
            }
        }
}

// ---------------------------------------------------------------------------
extern "C" void kernel_launch(void* const* d_in, const int* in_sizes, int n_in,
                              void* d_out, int out_size, void* d_ws, size_t ws_size,
                              hipStream_t stream)
{
    (void)in_sizes; (void)n_in; (void)out_size; (void)ws_size;
    const float* x  = (const float*)d_in[0];
    const float* Wk = (const float*)d_in[1];
    const float* Wq = (const float*)d_in[2];
    const float* Wv = (const float*)d_in[3];
    float* out = (float*)d_out;

    const size_t M1 = (size_t)1024 * 1024;
    ushort* ws  = (ushort*)d_ws;
    ushort* xb  = ws;                      // 8M elems
    ushort* Tb  = xb  + 8 * M1;            // 8M
    ushort* Vt  = Tb  + 8 * M1;            // 8M (4 x [1024][2048])
    ushort* Sb  = Vt  + 8 * M1;            // 16M (4 x [2048][2048])
    ushort* Wkt = Sb  + 16 * M1;           // 1M
    ushort* Wqt = Wkt + M1;                // 1M
    ushort* Wvb = Wqt + M1;                // 1M
    ushort* Mtr = Wvb + M1;                // 1M
    float*  rsum = (float*)(Mtr + M1);     // 4*9*2048 fp32 = 294 KB

    // 0) fused conversions (x, Wv straight; Wk, Wq transposed)
    cvt_all<<<6656, 256, 0, stream>>>(x, Wk, Wq, Wv, xb, Wvb, Wkt, Wqt);
    // 1) M = (Wq^T Wk)/32 stored transposed
    m_gemm<<<dim3(8, 8), 256, 0, stream>>>(Wkt, Wqt, Mtr);
    // 2) T = x@M (z=0), V^T (z=1); 256 blocks = 1/CU
    tv_gemm8<<<dim3(32, 4, 2), 512, 0, stream>>>(xb, Mtr, Wvb, Tb, Vt);
    // 3) scores -> exp(s) with causal mask + partial row-sums
    scores_gemm8<<<dim3(36, 4), 512, 0, stream>>>(Tb, xb, Sb, rsum);
    // 4) O = P @ V with fused normalize, 2 blocks/CU, heavy-first
    pv_one<<<dim3(16, 8, 4), 512, 0, stream>>>(Sb, Vt, rsum, out);
}